// Round 1
// baseline (244.768 us; speedup 1.0000x reference)
//
#include <hip/hip_runtime.h>
#include <math.h>

// GaussianMultiScore: B=524288 independent D=8 Gaussian-product scores.
// Memory-bound: 576B in / 4B out per batch element (~306MB total).
// One thread per batch element; all D=8 linear algebra fully unrolled in regs.
//
// Math: lam_new = cho0+cho1 = M (symmetric SPD, ~2I).
//  - Cholesky of reversed matrix Mt = J*M*J = Gt*Gt^T  (one Cholesky total)
//  - chol(inv(M)) diag = 1/diag(Gt) reversed  -> det_sum = sum 1/gt_ii^2
//  - sum(log diag_new^2) = -logdet(M) = -sum log gt_ii^2
//  - mu_new: solve Mt xt = J*eta (fwd+bwd triangular solves), mu_new = J*xt
//  - diff^T * lam_new * diff = || Gt^T * (J*diff) ||^2

constexpr float LOG_2PI_F = 1.8378770664093453f;
constexpr double TWO_PI_D = 6.283185307179586476925286766559;
constexpr float POW8_2PI =
    (float)(TWO_PI_D*TWO_PI_D*TWO_PI_D*TWO_PI_D*TWO_PI_D*TWO_PI_D*TWO_PI_D*TWO_PI_D);

#define TRI(i) (((i)*((i)+1))/2)

template <bool FIRST>
__device__ __forceinline__ void pass_accum(
    const float* __restrict__ muP, const float* __restrict__ choP, size_t b,
    float mt[36], float eta[8], float& quad_out, float& prod_out)
{
    float mu[8];
    {
        const float4* m4 = reinterpret_cast<const float4*>(muP + b * 8);
        float4 a = m4[0], c = m4[1];
        mu[0]=a.x; mu[1]=a.y; mu[2]=a.z; mu[3]=a.w;
        mu[4]=c.x; mu[5]=c.y; mu[6]=c.z; mu[7]=c.w;
    }
    const float4* M4 = reinterpret_cast<const float4*>(choP + b * 64);
    float quad = 0.0f, prod = 1.0f;
#pragma unroll
    for (int r = 0; r < 8; ++r) {
        float4 lo = M4[2*r], hi = M4[2*r+1];
        float row[8] = {lo.x, lo.y, lo.z, lo.w, hi.x, hi.y, hi.z, hi.w};
        float e = 0.0f;
#pragma unroll
        for (int j = 0; j < 8; ++j) e = fmaf(row[j], mu[j], e);
        if (FIRST) eta[r] = e; else eta[r] += e;
        quad = fmaf(mu[r], e, quad);
        prod *= row[r];
        // stash reversed: Mt[i][j] = M[7-i][7-j]; need lower tri j<=i  <=>  c>=r
#pragma unroll
        for (int c = r; c < 8; ++c) {
            int i = 7 - r, j = 7 - c;
            if (FIRST) mt[TRI(i) + j] = row[c];
            else       mt[TRI(i) + j] += row[c];
        }
    }
    quad_out = quad;
    prod_out = prod;
}

__global__ __launch_bounds__(256) void gms_kernel(
    const float* __restrict__ mu0, const float* __restrict__ mu1,
    const float* __restrict__ cho0, const float* __restrict__ cho1,
    const float* __restrict__ sample, float* __restrict__ out, int B)
{
    int b = blockIdx.x * 256 + threadIdx.x;
    if (b >= B) return;
    size_t bb = (size_t)b;

    // sample: 32B, L1-resident after first touch
    float s[8];
    {
        float4 v0 = reinterpret_cast<const float4*>(sample)[0];
        float4 v1 = reinterpret_cast<const float4*>(sample)[1];
        s[0]=v0.x; s[1]=v0.y; s[2]=v0.z; s[3]=v0.w;
        s[4]=v1.x; s[5]=v1.y; s[6]=v1.z; s[7]=v1.w;
    }

    float mt[36];   // reversed lower triangle of lam_new, then its Cholesky
    float eta[8];   // eta_new (natural order)
    float quad0, quad1, p0, p1;
    pass_accum<true >(mu0, cho0, bb, mt, eta, quad0, p0);
    pass_accum<false>(mu1, cho1, bb, mt, eta, quad1, p1);

    // ---- Cholesky of mt in place (D=8, fully unrolled) ----
    float ginv[8];
    float gprod = 1.0f;
#pragma unroll
    for (int j = 0; j < 8; ++j) {
        float d = mt[TRI(j) + j];
#pragma unroll
        for (int k = 0; k < j; ++k) {
            float v = mt[TRI(j) + k];
            d = fmaf(-v, v, d);
        }
        float sq = sqrtf(d);
        mt[TRI(j) + j] = sq;
        gprod *= sq;
        float inv = 1.0f / sq;
        ginv[j] = inv;
#pragma unroll
        for (int i = j + 1; i < 8; ++i) {
            float v = mt[TRI(i) + j];
#pragma unroll
            for (int k = 0; k < j; ++k)
                v = fmaf(-mt[TRI(i) + k], mt[TRI(j) + k], v);
            mt[TRI(i) + j] = v * inv;
        }
    }
    float logdetM = __logf(gprod * gprod);

    // ---- solve Mt * xt = reversed(eta) ----
    float er[8];
#pragma unroll
    for (int i = 0; i < 8; ++i) er[i] = eta[7 - i];
    float y[8];
#pragma unroll
    for (int i = 0; i < 8; ++i) {
        float v = er[i];
#pragma unroll
        for (int k = 0; k < i; ++k) v = fmaf(-mt[TRI(i) + k], y[k], v);
        y[i] = v * ginv[i];
    }
    float x[8];
#pragma unroll
    for (int ii = 7; ii >= 0; --ii) {
        float v = y[ii];
#pragma unroll
        for (int k = ii + 1; k < 8; ++k) v = fmaf(-mt[TRI(k) + ii], x[k], v);
        x[ii] = v * ginv[ii];
    }

    // quad_new = mu_new . eta_new  (reversal-invariant dot)
    float qn = 0.0f;
#pragma unroll
    for (int i = 0; i < 8; ++i) qn = fmaf(x[i], er[i], qn);

    // exp_part = -0.5 * diff^T M diff = -0.5 * ||Gt^T (J diff)||^2
    float dd[8];
#pragma unroll
    for (int i = 0; i < 8; ++i) dd[i] = x[i] - s[7 - i];
    float ep = 0.0f;
#pragma unroll
    for (int i = 0; i < 8; ++i) {
        float z = 0.0f;
#pragma unroll
        for (int k = i; k < 8; ++k) z = fmaf(mt[TRI(k) + i], dd[k], z);
        ep = fmaf(z, z, ep);
    }
    float exp_part = -0.5f * ep;

    // det (faithful: SUM of diag_new^2) = sum 1/gt_ii^2
    float det_sum = 0.0f;
#pragma unroll
    for (int i = 0; i < 8; ++i) det_sum = fmaf(ginv[i], ginv[i], det_sum);

    float sumlog0 = __logf(p0 * p0);
    float sumlog1 = __logf(p1 * p1);
    float zeta0   = -0.5f * (8.0f * LOG_2PI_F - sumlog0 + quad0);
    float zeta1   = -0.5f * (8.0f * LOG_2PI_F - sumlog1 + quad1);
    float zeta_n  = -0.5f * (8.0f * LOG_2PI_F + logdetM + qn);
    float scale   = zeta0 + zeta1 - zeta_n;

    out[b] = __expf(scale + exp_part) / sqrtf(POW8_2PI * det_sum);
}

extern "C" void kernel_launch(void* const* d_in, const int* in_sizes, int n_in,
                              void* d_out, int out_size, void* d_ws, size_t ws_size,
                              hipStream_t stream) {
    const float* mu0    = (const float*)d_in[0];
    const float* mu1    = (const float*)d_in[1];
    const float* cho0   = (const float*)d_in[2];
    const float* cho1   = (const float*)d_in[3];
    const float* sample = (const float*)d_in[4];
    float* out = (float*)d_out;
    int B = in_sizes[0] / 8;
    int blocks = (B + 255) / 256;
    gms_kernel<<<dim3(blocks), dim3(256), 0, stream>>>(
        mu0, mu1, cho0, cho1, sample, out, B);
}

// Round 3
// 52.128 us; speedup vs baseline: 4.6956x; 4.6956x over previous
//
#include <hip/hip_runtime.h>
#include <math.h>
#include <stdint.h>

// GaussianMultiScore: B=524288 independent D=8 Gaussian-product scores.
// Memory-bound: 576B in / 4B out per element (~306MB total).
// R1: per-thread stride-256B float4 gather over-fetched 2.7x (817MB), 245us.
// R2: LDS-staged cho via global_load_lds(16B) -> crashed: blockBase applied
//     twice in the global source address (OOB fault).
// R3: same design, offset bug fixed (stage_cho takes the UNOFFSET pointer).
//
// Math (one Cholesky total): lam_new = cho0+cho1 = M.
//  Mt = J*M*J = Gt*Gt^T;  diag(chol(inv(M))) = reversed 1/diag(Gt)
//  sum(log diag_new^2) = -logdet(M);  mu_new via two triangular solves;
//  diff^T M diff = ||Gt^T (J diff)||^2;  det_sum(faithful) = sum 1/gt_ii^2.

constexpr float LOG_2PI_F = 1.8378770664093453f;
constexpr double TWO_PI_D = 6.283185307179586476925286766559;
constexpr float POW8_2PI =
    (float)(TWO_PI_D*TWO_PI_D*TWO_PI_D*TWO_PI_D*TWO_PI_D*TWO_PI_D*TWO_PI_D*TWO_PI_D);

#define TRI(i) (((i)*((i)+1))/2)

typedef __attribute__((address_space(1))) const uint32_t glb_u32_t;
typedef __attribute__((address_space(3))) uint32_t       lds_u32_t;

// Stage 64 elements x 256B of cho into lds, swizzled so that the reader's
// slot (j ^ (elem&15)) holds logical float4 j. global_load_lds writes
// linearly (base + lane*16), so the swizzle is applied to the SOURCE address.
// choP is the UNOFFSET array base; element index e = blockBase + r.
__device__ __forceinline__ void stage_cho(const float* __restrict__ choP,
                                          size_t blockBase, int B,
                                          float* lds, int t)
{
#pragma unroll
    for (int i = 0; i < 16; ++i) {
        int g  = i * 64 + t;        // linear f4 slot in the 1024-f4 tile
        int r  = g >> 4;            // local element 0..63
        int s4 = g & 15;            // f4 slot within element
        int j  = s4 ^ (r & 15);     // logical f4 index whose data lands here
        size_t e = blockBase + (size_t)r;
        if (e >= (size_t)B) e = (size_t)B - 1;   // clamp (B%64==0 normally)
        __builtin_amdgcn_global_load_lds(
            (glb_u32_t*)(const void*)(choP + e * 64 + (size_t)(j * 4)),
            (lds_u32_t*)(void*)(lds + g * 4),
            16, 0, 0);
    }
}

template <bool FIRST>
__device__ __forceinline__ void pass_lds(
    const float* lds, int t, const float mu[8],
    float mt[36], float eta[8], float& quad_out, float& prod_out)
{
    const float4* L4 = reinterpret_cast<const float4*>(lds);
    const int base = t * 16;
    const int sw   = t & 15;
    float quad = 0.0f, prod = 1.0f;
#pragma unroll
    for (int r = 0; r < 8; ++r) {
        float4 lo = L4[base + ((2 * r)     ^ sw)];
        float4 hi = L4[base + ((2 * r + 1) ^ sw)];
        float row[8] = {lo.x, lo.y, lo.z, lo.w, hi.x, hi.y, hi.z, hi.w};
        float e = 0.0f;
#pragma unroll
        for (int j = 0; j < 8; ++j) e = fmaf(row[j], mu[j], e);
        if (FIRST) eta[r] = e; else eta[r] += e;
        quad = fmaf(mu[r], e, quad);
        prod *= row[r];
        // reversed lower triangle: Mt[i][j] = M[7-i][7-j], keep j<=i (c>=r)
#pragma unroll
        for (int c = r; c < 8; ++c) {
            int i = 7 - r, jj = 7 - c;
            if (FIRST) mt[TRI(i) + jj]  = row[c];
            else       mt[TRI(i) + jj] += row[c];
        }
    }
    quad_out = quad;
    prod_out = prod;
}

__global__ __launch_bounds__(64) void gms_kernel(
    const float* __restrict__ mu0, const float* __restrict__ mu1,
    const float* __restrict__ cho0, const float* __restrict__ cho1,
    const float* __restrict__ sample, float* __restrict__ out, int B)
{
    __shared__ float lds[64 * 64];   // 16KB -> 10 blocks/CU
    const int t = threadIdx.x;
    const size_t blockBase = (size_t)blockIdx.x * 64;
    const size_t bb = blockBase + (size_t)t;
    const size_t be = bb < (size_t)B ? bb : (size_t)B - 1;

    stage_cho(cho0, blockBase, B, lds, t);

    float mA[8], mB[8], s[8];
    {
        const float4* m4 = reinterpret_cast<const float4*>(mu0 + be * 8);
        float4 a = m4[0], c = m4[1];
        mA[0]=a.x; mA[1]=a.y; mA[2]=a.z; mA[3]=a.w;
        mA[4]=c.x; mA[5]=c.y; mA[6]=c.z; mA[7]=c.w;
    }
    {
        const float4* m4 = reinterpret_cast<const float4*>(mu1 + be * 8);
        float4 a = m4[0], c = m4[1];
        mB[0]=a.x; mB[1]=a.y; mB[2]=a.z; mB[3]=a.w;
        mB[4]=c.x; mB[5]=c.y; mB[6]=c.z; mB[7]=c.w;
    }
    {
        float4 v0 = reinterpret_cast<const float4*>(sample)[0];
        float4 v1 = reinterpret_cast<const float4*>(sample)[1];
        s[0]=v0.x; s[1]=v0.y; s[2]=v0.z; s[3]=v0.w;
        s[4]=v1.x; s[5]=v1.y; s[6]=v1.z; s[7]=v1.w;
    }

    __syncthreads();                 // vmcnt drain: cho0 tile resident

    float mt[36], eta[8];
    float quad0, quad1, p0, p1;
    pass_lds<true>(lds, t, mA, mt, eta, quad0, p0);

    __syncthreads();                 // all reads of buffer done
    stage_cho(cho1, blockBase, B, lds, t);
    __syncthreads();                 // cho1 tile resident

    pass_lds<false>(lds, t, mB, mt, eta, quad1, p1);

    // ---- Cholesky of mt in place (D=8, fully unrolled) ----
    float ginv[8];
    float gprod = 1.0f;
#pragma unroll
    for (int j = 0; j < 8; ++j) {
        float d = mt[TRI(j) + j];
#pragma unroll
        for (int k = 0; k < j; ++k) {
            float v = mt[TRI(j) + k];
            d = fmaf(-v, v, d);
        }
        float sq = sqrtf(d);
        mt[TRI(j) + j] = sq;
        gprod *= sq;
        float inv = 1.0f / sq;
        ginv[j] = inv;
#pragma unroll
        for (int i = j + 1; i < 8; ++i) {
            float v = mt[TRI(i) + j];
#pragma unroll
            for (int k = 0; k < j; ++k)
                v = fmaf(-mt[TRI(i) + k], mt[TRI(j) + k], v);
            mt[TRI(i) + j] = v * inv;
        }
    }
    float logdetM = __logf(gprod * gprod);

    // ---- solve Mt * xt = reversed(eta) ----
    float er[8];
#pragma unroll
    for (int i = 0; i < 8; ++i) er[i] = eta[7 - i];
    float y[8];
#pragma unroll
    for (int i = 0; i < 8; ++i) {
        float v = er[i];
#pragma unroll
        for (int k = 0; k < i; ++k) v = fmaf(-mt[TRI(i) + k], y[k], v);
        y[i] = v * ginv[i];
    }
    float x[8];
#pragma unroll
    for (int ii = 7; ii >= 0; --ii) {
        float v = y[ii];
#pragma unroll
        for (int k = ii + 1; k < 8; ++k) v = fmaf(-mt[TRI(k) + ii], x[k], v);
        x[ii] = v * ginv[ii];
    }

    float qn = 0.0f;
#pragma unroll
    for (int i = 0; i < 8; ++i) qn = fmaf(x[i], er[i], qn);

    float dd[8];
#pragma unroll
    for (int i = 0; i < 8; ++i) dd[i] = x[i] - s[7 - i];
    float ep = 0.0f;
#pragma unroll
    for (int i = 0; i < 8; ++i) {
        float z = 0.0f;
#pragma unroll
        for (int k = i; k < 8; ++k) z = fmaf(mt[TRI(k) + i], dd[k], z);
        ep = fmaf(z, z, ep);
    }
    float exp_part = -0.5f * ep;

    float det_sum = 0.0f;
#pragma unroll
    for (int i = 0; i < 8; ++i) det_sum = fmaf(ginv[i], ginv[i], det_sum);

    float sumlog0 = __logf(p0 * p0);
    float sumlog1 = __logf(p1 * p1);
    float zeta0   = -0.5f * (8.0f * LOG_2PI_F - sumlog0 + quad0);
    float zeta1   = -0.5f * (8.0f * LOG_2PI_F - sumlog1 + quad1);
    float zeta_n  = -0.5f * (8.0f * LOG_2PI_F + logdetM + qn);
    float scale   = zeta0 + zeta1 - zeta_n;

    float result = __expf(scale + exp_part) / sqrtf(POW8_2PI * det_sum);
    if (bb < (size_t)B) out[bb] = result;
}

extern "C" void kernel_launch(void* const* d_in, const int* in_sizes, int n_in,
                              void* d_out, int out_size, void* d_ws, size_t ws_size,
                              hipStream_t stream) {
    const float* mu0    = (const float*)d_in[0];
    const float* mu1    = (const float*)d_in[1];
    const float* cho0   = (const float*)d_in[2];
    const float* cho1   = (const float*)d_in[3];
    const float* sample = (const float*)d_in[4];
    float* out = (float*)d_out;
    int B = in_sizes[0] / 8;
    int blocks = (B + 63) / 64;
    gms_kernel<<<dim3(blocks), dim3(64), 0, stream>>>(
        mu0, mu1, cho0, cho1, sample, out, B);
}